// Round 5
// baseline (1315.544 us; speedup 1.0000x reference)
//
#include <hip/hip_runtime.h>
#include <hip/hip_bf16.h>
#include <math.h>

#define D 128
#define WS 136            // LDS row stride in shorts
#define FS 132            // LDS row stride in floats
#define PB 128            // partition blocks

typedef __attribute__((ext_vector_type(8))) short bf16x8;
typedef __attribute__((ext_vector_type(4))) float f32x4;

__device__ __forceinline__ unsigned short f2bf(float f){
  return (unsigned short)((__float_as_uint(f) + 0x8000u) >> 16);
}
__device__ __forceinline__ float bf2f(unsigned short h){
  return __uint_as_float(((unsigned)h) << 16);
}
__device__ __forceinline__ float bf2f_lo(unsigned v){
  return __uint_as_float(v << 16);
}
__device__ __forceinline__ float bf2f_hi(unsigned v){
  return __uint_as_float(v & 0xFFFF0000u);
}
__device__ __forceinline__ float gelu_fast(float v){
  float u = v * v;
  float arg = v * (1.5957691216f + 0.0713548163f * u);
  arg = fminf(arg, 60.0f);
  float e = __expf(arg);
  return v * e * __builtin_amdgcn_rcpf(e + 1.0f);
}

// ---- weights fp32 -> bf16 frag-major pair-interleaved ----
__global__ __launch_bounds__(256) void k_prep(const float* s0, const float* s1,
    const float* s2, const float* s3, const float* s4, const float* s5,
    unsigned short* dst){
  int gt = blockIdx.x * 256 + threadIdx.x;   // 0..12287
  int m = gt >> 11;
  int r = gt & 2047;
  int f = r >> 6, lane = r & 63;
  int t = f & 7, kk = f >> 3;
  int row = t * 16 + (lane & 15);
  int col = kk * 32 + (lane >> 4) * 8;
  const float* src;
  if (m == 0) src = s0; else if (m == 1) src = s1; else if (m == 2) src = s2;
  else if (m == 3) src = s3; else if (m == 4) src = s4; else src = s5;
  src += row * 128 + col;
  float4 a = *(const float4*)src;
  float4 bb = *(const float4*)(src + 4);
  bf16x8 o;
  o[0] = (short)f2bf(a.x);  o[1] = (short)f2bf(a.y);
  o[2] = (short)f2bf(a.z);  o[3] = (short)f2bf(a.w);
  o[4] = (short)f2bf(bb.x); o[5] = (short)f2bf(bb.y);
  o[6] = (short)f2bf(bb.z); o[7] = (short)f2bf(bb.w);
  int pair = m >> 1, half = m & 1;
  *(bf16x8*)(dst + (size_t)pair * 32768 + (((size_t)f * 2 + half) * 64 + lane) * 8) = o;
}

// ---- bucket partition: count (LDS hist, no global atomics) ----
__global__ __launch_bounds__(256) void k_pcount(const int* __restrict__ edst,
    int* __restrict__ cnt, int E, int nb, int epb){
  __shared__ int hist[512];
  for (int b = threadIdx.x; b < nb; b += 256) hist[b] = 0;
  __syncthreads();
  int start = blockIdx.x * epb;
  int end = min(E, start + epb);
  for (int e = start + threadIdx.x; e < end; e += 256)
    atomicAdd(&hist[edst[e] >> 7], 1);
  __syncthreads();
  for (int b = threadIdx.x; b < nb; b += 256) cnt[blockIdx.x * nb + b] = hist[b];
}

// ---- bucket partition: scan (single block) ----
__global__ __launch_bounds__(256) void k_pscan(const int* __restrict__ cnt,
    int* __restrict__ offs, int* __restrict__ bbase, int E, int nb){
  __shared__ int tot[512], base[512];
  int t = threadIdx.x;
  for (int b = t; b < nb; b += 256){
    int s = 0;
    for (int blk = 0; blk < PB; blk++) s += cnt[blk * nb + b];
    tot[b] = s;
  }
  __syncthreads();
  for (int b = t; b < nb; b += 256){
    int s = 0;
    for (int j = 0; j < b; j++) s += tot[j];
    base[b] = s;
  }
  __syncthreads();
  for (int b = t; b < nb; b += 256){
    bbase[b] = base[b];
    int run = base[b];
    for (int blk = 0; blk < PB; blk++){
      offs[blk * nb + b] = run;
      run += cnt[blk * nb + b];
    }
  }
  if (t == 0) bbase[nb] = E;
}

// ---- bucket partition: scatter (LDS-only atomics) ----
__global__ __launch_bounds__(256) void k_pscatter(const int* __restrict__ esrc,
    const int* __restrict__ edst, const int* __restrict__ offs,
    unsigned* __restrict__ ebuf, int E, int nb, int epb){
  __shared__ int loff[512];
  for (int b = threadIdx.x; b < nb; b += 256) loff[b] = offs[blockIdx.x * nb + b];
  __syncthreads();
  int start = blockIdx.x * epb;
  int end = min(E, start + epb);
  for (int e = start + threadIdx.x; e < end; e += 256){
    int s = esrc[e], d = edst[e];
    int b = d >> 7;
    int pos = atomicAdd(&loff[b], 1);
    ebuf[pos] = (unsigned)s | ((unsigned)(d & 127) << 16);
  }
}

// ---- bucketed mean aggregation: one block per 128-node bucket, fp32 LDS acc ----
__global__ __launch_bounds__(256) void k_bagg(const unsigned short* __restrict__ h,
    const unsigned* __restrict__ ebuf, const int* __restrict__ bbase,
    unsigned short* __restrict__ out, int N){
  extern __shared__ char sraw[];
  float* tile = (float*)sraw;                       // 128*128 fp32, slot = j*16+l16
  int* degS = (int*)(sraw + 128 * 128 * 4);         // 128 ints
  int tid = threadIdx.x;
  #pragma unroll
  for (int i = 0; i < 16; i++)
    *(float4*)(tile + (tid + 256 * i) * 4) = (float4){0.f, 0.f, 0.f, 0.f};
  if (tid < 128) degS[tid] = 0;
  __syncthreads();
  int b = blockIdx.x;
  int start = bbase[b], end = bbase[b + 1];
  int qw = tid >> 4, l16 = tid & 15;
  int i = start + qw;
  for (; i + 16 < end; i += 32){
    unsigned e0 = ebuf[i], e1 = ebuf[i + 16];
    int s0 = e0 & 0xFFFF, d0 = e0 >> 16;
    int s1 = e1 & 0xFFFF, d1 = e1 >> 16;
    uint4 v0 = *(const uint4*)(h + (size_t)s0 * D + l16 * 8);
    uint4 v1 = *(const uint4*)(h + (size_t)s1 * D + l16 * 8);
    if (l16 == 0){ atomicAdd(&degS[d0], 1); atomicAdd(&degS[d1], 1); }
    float* t0 = tile + d0 * 128 + l16;
    atomicAdd(t0 +   0, bf2f_lo(v0.x)); atomicAdd(t0 +  16, bf2f_hi(v0.x));
    atomicAdd(t0 +  32, bf2f_lo(v0.y)); atomicAdd(t0 +  48, bf2f_hi(v0.y));
    atomicAdd(t0 +  64, bf2f_lo(v0.z)); atomicAdd(t0 +  80, bf2f_hi(v0.z));
    atomicAdd(t0 +  96, bf2f_lo(v0.w)); atomicAdd(t0 + 112, bf2f_hi(v0.w));
    float* t1 = tile + d1 * 128 + l16;
    atomicAdd(t1 +   0, bf2f_lo(v1.x)); atomicAdd(t1 +  16, bf2f_hi(v1.x));
    atomicAdd(t1 +  32, bf2f_lo(v1.y)); atomicAdd(t1 +  48, bf2f_hi(v1.y));
    atomicAdd(t1 +  64, bf2f_lo(v1.z)); atomicAdd(t1 +  80, bf2f_hi(v1.z));
    atomicAdd(t1 +  96, bf2f_lo(v1.w)); atomicAdd(t1 + 112, bf2f_hi(v1.w));
  }
  if (i < end){
    unsigned e0 = ebuf[i];
    int s0 = e0 & 0xFFFF, d0 = e0 >> 16;
    uint4 v0 = *(const uint4*)(h + (size_t)s0 * D + l16 * 8);
    if (l16 == 0) atomicAdd(&degS[d0], 1);
    float* t0 = tile + d0 * 128 + l16;
    atomicAdd(t0 +   0, bf2f_lo(v0.x)); atomicAdd(t0 +  16, bf2f_hi(v0.x));
    atomicAdd(t0 +  32, bf2f_lo(v0.y)); atomicAdd(t0 +  48, bf2f_hi(v0.y));
    atomicAdd(t0 +  64, bf2f_lo(v0.z)); atomicAdd(t0 +  80, bf2f_hi(v0.z));
    atomicAdd(t0 +  96, bf2f_lo(v0.w)); atomicAdd(t0 + 112, bf2f_hi(v0.w));
  }
  __syncthreads();
  int nb0 = b << 7;
  #pragma unroll
  for (int r = 0; r < 8; r++){
    int dloc = r * 16 + qw;
    int node = nb0 + dloc;
    if (node < N){
      float inv = 1.0f / (float)max(degS[dloc], 1);
      const float* tp = tile + dloc * 128 + l16;
      uint4 o;
      o.x = ((unsigned)f2bf(tp[ 16] * inv) << 16) | f2bf(tp[  0] * inv);
      o.y = ((unsigned)f2bf(tp[ 48] * inv) << 16) | f2bf(tp[ 32] * inv);
      o.z = ((unsigned)f2bf(tp[ 80] * inv) << 16) | f2bf(tp[ 64] * inv);
      o.w = ((unsigned)f2bf(tp[112] * inv) << 16) | f2bf(tp[ 96] * inv);
      *(uint4*)(out + (size_t)node * D + l16 * 8) = o;
    }
  }
}

// ---- input layer: 16 nodes/wave, 64/block; sbuf=bf16(x@sc^T+b), hbuf=gelu(x@dp^T+b) ----
__global__ __launch_bounds__(256) void k_in(const float* __restrict__ x,
    const unsigned short* __restrict__ wp,
    const float* __restrict__ scb, const float* __restrict__ dpb,
    unsigned short* __restrict__ sbuf, unsigned short* __restrict__ hbuf, int N){
  __shared__ unsigned short tile[64 * WS];
  int tid = threadIdx.x, w = tid >> 6, lane = tid & 63, quad = lane >> 4, l16 = lane & 15;
  int nbb = blockIdx.x * 64;
  int nb = nbb + w * 16;
  int arow = min(nb + l16, N - 1);
  f32x4 acc[2][8];
  #pragma unroll
  for (int m = 0; m < 2; m++)
    #pragma unroll
    for (int t = 0; t < 8; t++) acc[m][t] = (f32x4){0.f, 0.f, 0.f, 0.f};
  #pragma unroll
  for (int kk = 0; kk < 4; kk++){
    const float* xp = x + (size_t)arow * D + kk * 32 + quad * 8;
    float4 xa = *(const float4*)xp;
    float4 xb = *(const float4*)(xp + 4);
    bf16x8 a;
    a[0] = (short)f2bf(xa.x); a[1] = (short)f2bf(xa.y);
    a[2] = (short)f2bf(xa.z); a[3] = (short)f2bf(xa.w);
    a[4] = (short)f2bf(xb.x); a[5] = (short)f2bf(xb.y);
    a[6] = (short)f2bf(xb.z); a[7] = (short)f2bf(xb.w);
    #pragma unroll
    for (int t = 0; t < 8; t++){
      size_t fo = (((size_t)(kk * 8 + t) * 2) * 64 + lane) * 8;
      bf16x8 b0 = *(const bf16x8*)(wp + fo);
      bf16x8 b1 = *(const bf16x8*)(wp + fo + 512);
      acc[0][t] = __builtin_amdgcn_mfma_f32_16x16x32_bf16(a, b0, acc[0][t], 0, 0, 0);
      acc[1][t] = __builtin_amdgcn_mfma_f32_16x16x32_bf16(a, b1, acc[1][t], 0, 0, 0);
    }
  }
  #pragma unroll
  for (int m = 0; m < 2; m++){
    const float* bias = m ? dpb : scb;
    #pragma unroll
    for (int t = 0; t < 8; t++){
      float bv = bias[t * 16 + l16];
      #pragma unroll
      for (int r = 0; r < 4; r++){
        int nl = w * 16 + quad * 4 + r;
        float v = acc[m][t][r] + bv;
        if (m) v = gelu_fast(v);
        tile[nl * WS + t * 16 + l16] = f2bf(v);
      }
    }
    __syncthreads();
    unsigned short* dst = m ? hbuf : sbuf;
    #pragma unroll
    for (int i = 0; i < 4; i++){
      int c = tid + 256 * i;
      int nl = c >> 4, j = c & 15;
      int node = nbb + nl;
      if (node < N)
        *(bf16x8*)(dst + (size_t)node * D + j * 8) = *(const bf16x8*)(tile + nl * WS + j * 8);
    }
    __syncthreads();
  }
}

// ---- SAGE layer ----
__global__ __launch_bounds__(256) void k_g(
    const unsigned short* __restrict__ hin, const unsigned short* __restrict__ mbuf,
    const unsigned short* __restrict__ wp,
    const float* __restrict__ lb, const float* __restrict__ gamma,
    const float* __restrict__ beta,
    const unsigned short* __restrict__ sbuf,
    unsigned short* __restrict__ hout, float* __restrict__ fout, int N, int mode){
  extern __shared__ char smraw[];
  unsigned short* stile = (unsigned short*)smraw;
  float* ftile = (float*)smraw;
  int tid = threadIdx.x, w = tid >> 6, lane = tid & 63, quad = lane >> 4, l16 = lane & 15;
  int nbb = blockIdx.x * 64;
  int nb = nbb + w * 16;
  int arow = min(nb + l16, N - 1);
  f32x4 acc[8];
  #pragma unroll
  for (int t = 0; t < 8; t++) acc[t] = (f32x4){0.f, 0.f, 0.f, 0.f};
  #pragma unroll
  for (int kk = 0; kk < 4; kk++){
    int co = kk * 32 + quad * 8;
    bf16x8 am = *(const bf16x8*)(mbuf + (size_t)arow * D + co);
    bf16x8 ah = *(const bf16x8*)(hin + (size_t)arow * D + co);
    #pragma unroll
    for (int t = 0; t < 8; t++){
      size_t fo = (((size_t)(kk * 8 + t) * 2) * 64 + lane) * 8;
      bf16x8 bl = *(const bf16x8*)(wp + fo);
      bf16x8 br = *(const bf16x8*)(wp + fo + 512);
      acc[t] = __builtin_amdgcn_mfma_f32_16x16x32_bf16(am, bl, acc[t], 0, 0, 0);
      acc[t] = __builtin_amdgcn_mfma_f32_16x16x32_bf16(ah, br, acc[t], 0, 0, 0);
    }
  }
  float lbv[8], gv[8], bv[8];
  #pragma unroll
  for (int t = 0; t < 8; t++){
    lbv[t] = lb[t * 16 + l16];
    gv[t] = gamma[t * 16 + l16];
    bv[t] = beta[t * 16 + l16];
  }
  float mu[4], rs[4];
  #pragma unroll
  for (int r = 0; r < 4; r++){
    float s = 0.f, qq = 0.f;
    #pragma unroll
    for (int t = 0; t < 8; t++){
      float v = acc[t][r] + lbv[t];
      acc[t][r] = v;
      s += v; qq += v * v;
    }
    s += __shfl_xor(s, 1); qq += __shfl_xor(qq, 1);
    s += __shfl_xor(s, 2); qq += __shfl_xor(qq, 2);
    s += __shfl_xor(s, 4); qq += __shfl_xor(qq, 4);
    s += __shfl_xor(s, 8); qq += __shfl_xor(qq, 8);
    float m_ = s * (1.f / 128.f);
    mu[r] = m_;
    rs[r] = rsqrtf(qq * (1.f / 128.f) - m_ * m_ + 1e-5f);
  }
  if (mode == 0){
    #pragma unroll
    for (int t = 0; t < 8; t++)
      #pragma unroll
      for (int r = 0; r < 4; r++){
        int nl = w * 16 + quad * 4 + r;
        float v = (acc[t][r] - mu[r]) * rs[r] * gv[t] + bv[t];
        stile[nl * WS + t * 16 + l16] = f2bf(gelu_fast(v));
      }
    __syncthreads();
    #pragma unroll
    for (int i = 0; i < 4; i++){
      int c = tid + 256 * i;
      int nl = c >> 4, j = c & 15;
      int node = nbb + nl;
      if (node < N)
        *(bf16x8*)(hout + (size_t)node * D + j * 8) = *(const bf16x8*)(stile + nl * WS + j * 8);
    }
  } else {
    #pragma unroll
    for (int i = 0; i < 4; i++){
      int c = tid + 256 * i;
      int nl = c >> 4, j = c & 15;
      int node = nbb + nl;
      bf16x8 v = (bf16x8){0,0,0,0,0,0,0,0};
      if (node < N) v = *(const bf16x8*)(sbuf + (size_t)node * D + j * 8);
      *(bf16x8*)(stile + nl * WS + j * 8) = v;
    }
    __syncthreads();
    float sc[8][4];
    #pragma unroll
    for (int t = 0; t < 8; t++)
      #pragma unroll
      for (int r = 0; r < 4; r++){
        int nl = w * 16 + quad * 4 + r;
        sc[t][r] = bf2f(stile[nl * WS + t * 16 + l16]);
      }
    __syncthreads();
    #pragma unroll
    for (int t = 0; t < 8; t++)
      #pragma unroll
      for (int r = 0; r < 4; r++){
        int nl = w * 16 + quad * 4 + r;
        float v = (acc[t][r] - mu[r]) * rs[r] * gv[t] + bv[t];
        ftile[nl * FS + t * 16 + l16] = gelu_fast(v + sc[t][r]);
      }
    __syncthreads();
    #pragma unroll
    for (int i = 0; i < 8; i++){
      int c = tid + 256 * i;
      int nl = c >> 5, j = c & 31;
      int node = nbb + nl;
      if (node < N)
        *(float4*)(fout + (size_t)node * D + j * 4) = *(const float4*)(ftile + nl * FS + j * 4);
    }
  }
}

extern "C" void kernel_launch(void* const* d_in, const int* in_sizes, int n_in,
                              void* d_out, int out_size, void* d_ws, size_t ws_size,
                              hipStream_t stream){
  const float* x     = (const float*)d_in[0];
  const int*   edges = (const int*)d_in[1];
  const float* dp_w  = (const float*)d_in[2];
  const float* dp_b  = (const float*)d_in[3];
  const float* sc_w  = (const float*)d_in[4];
  const float* sc_b  = (const float*)d_in[5];
  const float* g1_lw = (const float*)d_in[6];
  const float* g1_lb = (const float*)d_in[7];
  const float* g1_rw = (const float*)d_in[8];
  const float* n1_g  = (const float*)d_in[9];
  const float* n1_b  = (const float*)d_in[10];
  const float* g2_lw = (const float*)d_in[11];
  const float* g2_lb = (const float*)d_in[12];
  const float* g2_rw = (const float*)d_in[13];
  const float* n2_g  = (const float*)d_in[14];
  const float* n2_b  = (const float*)d_in[15];

  const int N = in_sizes[0] / D;
  const int E = in_sizes[1] / 2;
  const int* esrc = edges;
  const int* edst = edges + E;
  const int nb = (N + 127) >> 7;            // buckets (<=512 for N<=65536)
  const int epb = (E + PB - 1) / PB;

  char* base = (char*)d_ws;
  size_t cur = 0;
  auto carve = [&](size_t b) -> char* {
    char* p = base + cur;
    cur = (cur + b + 255) & ~(size_t)255;
    return p;
  };
  unsigned* ebuf = (unsigned*)carve((size_t)E * 4);
  int* cnt       = (int*)carve((size_t)PB * nb * 4);
  int* offs      = (int*)carve((size_t)PB * nb * 4);
  int* bbase     = (int*)carve((size_t)(nb + 1) * 4);
  unsigned short* wb   = (unsigned short*)carve((size_t)3 * 32768 * 2);
  unsigned short* hbuf = (unsigned short*)carve((size_t)N * D * 2);
  unsigned short* mbuf = (unsigned short*)carve((size_t)N * D * 2);
  unsigned short* sbuf = (unsigned short*)carve((size_t)N * D * 2);

  unsigned short* wp0 = wb;
  unsigned short* wp1 = wb + 32768;
  unsigned short* wp2 = wb + 2 * 32768;

  float* out = (float*)d_out;

  k_prep<<<48, 256, 0, stream>>>(sc_w, dp_w, g1_lw, g1_rw, g2_lw, g2_rw, wb);
  k_pcount<<<PB, 256, 0, stream>>>(edst, cnt, E, nb, epb);

  const int nin = (N + 63) / 64;
  k_in<<<nin, 256, 0, stream>>>(x, wp0, sc_b, dp_b, sbuf, hbuf, N);

  k_pscan<<<1, 256, 0, stream>>>(cnt, offs, bbase, E, nb);
  k_pscatter<<<PB, 256, 0, stream>>>(esrc, edst, offs, ebuf, E, nb, epb);

  const size_t bagg_lds = 128 * 128 * 4 + 128 * 4;
  k_bagg<<<nb, 256, bagg_lds, stream>>>(hbuf, ebuf, bbase, mbuf, N);
  k_g<<<nin, 256, 17408, stream>>>(hbuf, mbuf, wp1, g1_lb, n1_g, n1_b,
                                   nullptr, hbuf, nullptr, N, 0);
  k_bagg<<<nb, 256, bagg_lds, stream>>>(hbuf, ebuf, bbase, mbuf, N);
  k_g<<<nin, 256, 33792, stream>>>(hbuf, mbuf, wp2, g2_lb, n2_g, n2_b,
                                   sbuf, nullptr, out, N, 1);
}

// Round 6
// 265.905 us; speedup vs baseline: 4.9474x; 4.9474x over previous
//
#include <hip/hip_runtime.h>
#include <hip/hip_bf16.h>
#include <math.h>

#define D 128
#define WS 136            // LDS row stride in shorts
#define FS 132            // LDS row stride in floats
#define PB 128            // partition blocks

typedef __attribute__((ext_vector_type(8))) short bf16x8;
typedef __attribute__((ext_vector_type(4))) float f32x4;

__device__ __forceinline__ unsigned short f2bf(float f){
  return (unsigned short)((__float_as_uint(f) + 0x8000u) >> 16);
}
__device__ __forceinline__ float bf2f(unsigned short h){
  return __uint_as_float(((unsigned)h) << 16);
}
__device__ __forceinline__ float bf2f_lo(unsigned v){
  return __uint_as_float(v << 16);
}
__device__ __forceinline__ float bf2f_hi(unsigned v){
  return __uint_as_float(v & 0xFFFF0000u);
}
__device__ __forceinline__ float gelu_fast(float v){
  float u = v * v;
  float arg = v * (1.5957691216f + 0.0713548163f * u);
  arg = fminf(arg, 60.0f);
  float e = __expf(arg);
  return v * e * __builtin_amdgcn_rcpf(e + 1.0f);
}

// ---- weights fp32 -> bf16 frag-major pair-interleaved ----
__global__ __launch_bounds__(256) void k_prep(const float* s0, const float* s1,
    const float* s2, const float* s3, const float* s4, const float* s5,
    unsigned short* dst){
  int gt = blockIdx.x * 256 + threadIdx.x;   // 0..12287
  int m = gt >> 11;
  int r = gt & 2047;
  int f = r >> 6, lane = r & 63;
  int t = f & 7, kk = f >> 3;
  int row = t * 16 + (lane & 15);
  int col = kk * 32 + (lane >> 4) * 8;
  const float* src;
  if (m == 0) src = s0; else if (m == 1) src = s1; else if (m == 2) src = s2;
  else if (m == 3) src = s3; else if (m == 4) src = s4; else src = s5;
  src += row * 128 + col;
  float4 a = *(const float4*)src;
  float4 bb = *(const float4*)(src + 4);
  bf16x8 o;
  o[0] = (short)f2bf(a.x);  o[1] = (short)f2bf(a.y);
  o[2] = (short)f2bf(a.z);  o[3] = (short)f2bf(a.w);
  o[4] = (short)f2bf(bb.x); o[5] = (short)f2bf(bb.y);
  o[6] = (short)f2bf(bb.z); o[7] = (short)f2bf(bb.w);
  int pair = m >> 1, half = m & 1;
  *(bf16x8*)(dst + (size_t)pair * 32768 + (((size_t)f * 2 + half) * 64 + lane) * 8) = o;
}

// ---- bucket partition: count (LDS hist only) ----
__global__ __launch_bounds__(256) void k_pcount(const int* __restrict__ edst,
    int* __restrict__ cnt, int E, int nbuck, int epb){
  __shared__ int hist[512];
  for (int b = threadIdx.x; b < nbuck; b += 256) hist[b] = 0;
  __syncthreads();
  int start = blockIdx.x * epb;
  int end = min(E, start + epb);
  for (int e = start + threadIdx.x; e < end; e += 256)
    atomicAdd(&hist[edst[e] >> 7], 1);
  __syncthreads();
  for (int b = threadIdx.x; b < nbuck; b += 256) cnt[blockIdx.x * nbuck + b] = hist[b];
}

// ---- bucket partition: scan (single block) ----
__global__ __launch_bounds__(256) void k_pscan(const int* __restrict__ cnt,
    int* __restrict__ offs, int* __restrict__ bbase, int E, int nbuck){
  __shared__ int tot[512], base[512];
  int t = threadIdx.x;
  for (int b = t; b < nbuck; b += 256){
    int s = 0;
    for (int blk = 0; blk < PB; blk++) s += cnt[blk * nbuck + b];
    tot[b] = s;
  }
  __syncthreads();
  for (int b = t; b < nbuck; b += 256){
    int s = 0;
    for (int j = 0; j < b; j++) s += tot[j];
    base[b] = s;
  }
  __syncthreads();
  for (int b = t; b < nbuck; b += 256){
    bbase[b] = base[b];
    int run = base[b];
    for (int blk = 0; blk < PB; blk++){
      offs[blk * nbuck + b] = run;
      run += cnt[blk * nbuck + b];
    }
  }
  if (t == 0) bbase[nbuck] = E;
}

// ---- bucket partition: scatter (LDS-only atomics) -> ebuf = src | dloc<<16 ----
__global__ __launch_bounds__(256) void k_pscatter(const int* __restrict__ esrc,
    const int* __restrict__ edst, const int* __restrict__ offs,
    unsigned* __restrict__ ebuf, int E, int nbuck, int epb){
  __shared__ int loff[512];
  for (int b = threadIdx.x; b < nbuck; b += 256) loff[b] = offs[blockIdx.x * nbuck + b];
  __syncthreads();
  int start = blockIdx.x * epb;
  int end = min(E, start + epb);
  for (int e = start + threadIdx.x; e < end; e += 256){
    int s = esrc[e], d = edst[e];
    int b = d >> 7;
    int pos = atomicAdd(&loff[b], 1);
    ebuf[pos] = (unsigned)s | ((unsigned)(d & 127) << 16);
  }
}

// ---- per-bucket counting sort -> node-sorted csr + global off (LDS atomics) ----
__global__ __launch_bounds__(256) void k_csr(const unsigned* __restrict__ ebuf,
    const int* __restrict__ bbase, int* __restrict__ off, int* __restrict__ csr,
    int N, int E){
  __shared__ int cnt[128], pref[128], cur[128];
  int b = blockIdx.x, tid = threadIdx.x;
  int start = bbase[b], end = bbase[b + 1];
  if (tid < 128) cnt[tid] = 0;
  __syncthreads();
  for (int e = start + tid; e < end; e += 256)
    atomicAdd(&cnt[ebuf[e] >> 16], 1);
  __syncthreads();
  if (tid < 128) pref[tid] = cnt[tid];
  __syncthreads();
  for (int ofs = 1; ofs < 128; ofs <<= 1){
    int v = 0;
    if (tid < 128 && tid >= ofs) v = pref[tid - ofs];
    __syncthreads();
    if (tid < 128) pref[tid] += v;
    __syncthreads();
  }
  if (tid < 128){
    int ex = pref[tid] - cnt[tid];    // exclusive prefix
    cur[tid] = ex;
    int node = b * 128 + tid;
    if (node < N) off[node] = start + ex;
  }
  if (b == 0 && tid == 0) off[N] = E;
  __syncthreads();
  for (int e = start + tid; e < end; e += 256){
    unsigned u = ebuf[e];
    int d = u >> 16;
    int p = atomicAdd(&cur[d], 1);
    csr[start + p] = (int)(u & 0xFFFFu);
  }
}

// ---- input layer: 16 nodes/wave, 64/block; sbuf=bf16(x@sc^T+b), hbuf=gelu(x@dp^T+b) ----
__global__ __launch_bounds__(256) void k_in(const float* __restrict__ x,
    const unsigned short* __restrict__ wp,
    const float* __restrict__ scb, const float* __restrict__ dpb,
    unsigned short* __restrict__ sbuf, unsigned short* __restrict__ hbuf, int N){
  __shared__ unsigned short tile[64 * WS];
  int tid = threadIdx.x, w = tid >> 6, lane = tid & 63, quad = lane >> 4, l16 = lane & 15;
  int nbb = blockIdx.x * 64;
  int nb = nbb + w * 16;
  int arow = min(nb + l16, N - 1);
  f32x4 acc[2][8];
  #pragma unroll
  for (int m = 0; m < 2; m++)
    #pragma unroll
    for (int t = 0; t < 8; t++) acc[m][t] = (f32x4){0.f, 0.f, 0.f, 0.f};
  #pragma unroll
  for (int kk = 0; kk < 4; kk++){
    const float* xp = x + (size_t)arow * D + kk * 32 + quad * 8;
    float4 xa = *(const float4*)xp;
    float4 xb = *(const float4*)(xp + 4);
    bf16x8 a;
    a[0] = (short)f2bf(xa.x); a[1] = (short)f2bf(xa.y);
    a[2] = (short)f2bf(xa.z); a[3] = (short)f2bf(xa.w);
    a[4] = (short)f2bf(xb.x); a[5] = (short)f2bf(xb.y);
    a[6] = (short)f2bf(xb.z); a[7] = (short)f2bf(xb.w);
    #pragma unroll
    for (int t = 0; t < 8; t++){
      size_t fo = (((size_t)(kk * 8 + t) * 2) * 64 + lane) * 8;
      bf16x8 b0 = *(const bf16x8*)(wp + fo);
      bf16x8 b1 = *(const bf16x8*)(wp + fo + 512);
      acc[0][t] = __builtin_amdgcn_mfma_f32_16x16x32_bf16(a, b0, acc[0][t], 0, 0, 0);
      acc[1][t] = __builtin_amdgcn_mfma_f32_16x16x32_bf16(a, b1, acc[1][t], 0, 0, 0);
    }
  }
  #pragma unroll
  for (int m = 0; m < 2; m++){
    const float* bias = m ? dpb : scb;
    #pragma unroll
    for (int t = 0; t < 8; t++){
      float bv = bias[t * 16 + l16];
      #pragma unroll
      for (int r = 0; r < 4; r++){
        int nl = w * 16 + quad * 4 + r;
        float v = acc[m][t][r] + bv;
        if (m) v = gelu_fast(v);
        tile[nl * WS + t * 16 + l16] = f2bf(v);
      }
    }
    __syncthreads();
    unsigned short* dst = m ? hbuf : sbuf;
    #pragma unroll
    for (int i = 0; i < 4; i++){
      int c = tid + 256 * i;
      int nl = c >> 4, j = c & 15;
      int node = nbb + nl;
      if (node < N)
        *(bf16x8*)(dst + (size_t)node * D + j * 8) = *(const bf16x8*)(tile + nl * WS + j * 8);
    }
    __syncthreads();
  }
}

// ---- fused SAGE layer: per-lane register gather of neighbor mean +
//      dual MFMA + LN (+gelu / +shortcut) ----
__global__ __launch_bounds__(256) void k_gf(
    const unsigned short* __restrict__ hin,
    const int* __restrict__ off, const int* __restrict__ csr,
    const unsigned short* __restrict__ wp,
    const float* __restrict__ lb, const float* __restrict__ gamma,
    const float* __restrict__ beta,
    const unsigned short* __restrict__ sbuf,
    unsigned short* __restrict__ hout, float* __restrict__ fout, int N, int mode){
  extern __shared__ char smraw[];
  unsigned short* stile = (unsigned short*)smraw;
  float* ftile = (float*)smraw;
  int tid = threadIdx.x, w = tid >> 6, lane = tid & 63, quad = lane >> 4, l16 = lane & 15;
  int nbb = blockIdx.x * 64;
  int nb = nbb + w * 16;
  int node = min(nb + l16, N - 1);
  int s0 = off[node], s1 = off[node + 1];
  int deg = s1 - s0;
  // gather mean of neighbor rows: lane (l16,quad) covers 4x16B slices of each row
  float am[4][8];
  #pragma unroll
  for (int k = 0; k < 4; k++)
    #pragma unroll
    for (int c = 0; c < 8; c++) am[k][c] = 0.f;
  int j = s0;
  for (; j + 1 < s1; j += 2){
    int sA = csr[j], sB = csr[j + 1];
    const unsigned short* pA = hin + (size_t)sA * D + quad * 8;
    const unsigned short* pB = hin + (size_t)sB * D + quad * 8;
    #pragma unroll
    for (int k = 0; k < 4; k++){
      uint4 vA = *(const uint4*)(pA + k * 32);
      uint4 vB = *(const uint4*)(pB + k * 32);
      am[k][0] += bf2f_lo(vA.x) + bf2f_lo(vB.x);
      am[k][1] += bf2f_hi(vA.x) + bf2f_hi(vB.x);
      am[k][2] += bf2f_lo(vA.y) + bf2f_lo(vB.y);
      am[k][3] += bf2f_hi(vA.y) + bf2f_hi(vB.y);
      am[k][4] += bf2f_lo(vA.z) + bf2f_lo(vB.z);
      am[k][5] += bf2f_hi(vA.z) + bf2f_hi(vB.z);
      am[k][6] += bf2f_lo(vA.w) + bf2f_lo(vB.w);
      am[k][7] += bf2f_hi(vA.w) + bf2f_hi(vB.w);
    }
  }
  if (j < s1){
    int sA = csr[j];
    const unsigned short* pA = hin + (size_t)sA * D + quad * 8;
    #pragma unroll
    for (int k = 0; k < 4; k++){
      uint4 vA = *(const uint4*)(pA + k * 32);
      am[k][0] += bf2f_lo(vA.x); am[k][1] += bf2f_hi(vA.x);
      am[k][2] += bf2f_lo(vA.y); am[k][3] += bf2f_hi(vA.y);
      am[k][4] += bf2f_lo(vA.z); am[k][5] += bf2f_hi(vA.z);
      am[k][6] += bf2f_lo(vA.w); am[k][7] += bf2f_hi(vA.w);
    }
  }
  float inv = 1.0f / (float)(deg > 1 ? deg : 1);
  bf16x8 ap[4], ah[4];
  #pragma unroll
  for (int k = 0; k < 4; k++){
    ah[k] = *(const bf16x8*)(hin + (size_t)node * D + k * 32 + quad * 8);
    #pragma unroll
    for (int c = 0; c < 8; c++) ap[k][c] = (short)f2bf(am[k][c] * inv);
  }
  f32x4 acc[8];
  #pragma unroll
  for (int t = 0; t < 8; t++) acc[t] = (f32x4){0.f, 0.f, 0.f, 0.f};
  #pragma unroll
  for (int k = 0; k < 4; k++){
    #pragma unroll
    for (int t = 0; t < 8; t++){
      size_t fo = (((size_t)(k * 8 + t) * 2) * 64 + lane) * 8;
      bf16x8 bl = *(const bf16x8*)(wp + fo);
      bf16x8 br = *(const bf16x8*)(wp + fo + 512);
      acc[t] = __builtin_amdgcn_mfma_f32_16x16x32_bf16(ap[k], bl, acc[t], 0, 0, 0);
      acc[t] = __builtin_amdgcn_mfma_f32_16x16x32_bf16(ah[k], br, acc[t], 0, 0, 0);
    }
  }
  float lbv[8], gv[8], bv[8];
  #pragma unroll
  for (int t = 0; t < 8; t++){
    lbv[t] = lb[t * 16 + l16];
    gv[t] = gamma[t * 16 + l16];
    bv[t] = beta[t * 16 + l16];
  }
  float mu[4], rs[4];
  #pragma unroll
  for (int r = 0; r < 4; r++){
    float s = 0.f, qq = 0.f;
    #pragma unroll
    for (int t = 0; t < 8; t++){
      float v = acc[t][r] + lbv[t];
      acc[t][r] = v;
      s += v; qq += v * v;
    }
    s += __shfl_xor(s, 1); qq += __shfl_xor(qq, 1);
    s += __shfl_xor(s, 2); qq += __shfl_xor(qq, 2);
    s += __shfl_xor(s, 4); qq += __shfl_xor(qq, 4);
    s += __shfl_xor(s, 8); qq += __shfl_xor(qq, 8);
    float m_ = s * (1.f / 128.f);
    mu[r] = m_;
    rs[r] = rsqrtf(qq * (1.f / 128.f) - m_ * m_ + 1e-5f);
  }
  if (mode == 0){
    #pragma unroll
    for (int t = 0; t < 8; t++)
      #pragma unroll
      for (int r = 0; r < 4; r++){
        int nl = w * 16 + quad * 4 + r;
        float v = (acc[t][r] - mu[r]) * rs[r] * gv[t] + bv[t];
        stile[nl * WS + t * 16 + l16] = f2bf(gelu_fast(v));
      }
    __syncthreads();
    #pragma unroll
    for (int i = 0; i < 4; i++){
      int c = tid + 256 * i;
      int nl = c >> 4, jj = c & 15;
      int nd = nbb + nl;
      if (nd < N)
        *(bf16x8*)(hout + (size_t)nd * D + jj * 8) = *(const bf16x8*)(stile + nl * WS + jj * 8);
    }
  } else {
    #pragma unroll
    for (int i = 0; i < 4; i++){
      int c = tid + 256 * i;
      int nl = c >> 4, jj = c & 15;
      int nd = nbb + nl;
      bf16x8 v = (bf16x8){0,0,0,0,0,0,0,0};
      if (nd < N) v = *(const bf16x8*)(sbuf + (size_t)nd * D + jj * 8);
      *(bf16x8*)(stile + nl * WS + jj * 8) = v;
    }
    __syncthreads();
    float sc[8][4];
    #pragma unroll
    for (int t = 0; t < 8; t++)
      #pragma unroll
      for (int r = 0; r < 4; r++){
        int nl = w * 16 + quad * 4 + r;
        sc[t][r] = bf2f(stile[nl * WS + t * 16 + l16]);
      }
    __syncthreads();
    #pragma unroll
    for (int t = 0; t < 8; t++)
      #pragma unroll
      for (int r = 0; r < 4; r++){
        int nl = w * 16 + quad * 4 + r;
        float v = (acc[t][r] - mu[r]) * rs[r] * gv[t] + bv[t];
        ftile[nl * FS + t * 16 + l16] = gelu_fast(v + sc[t][r]);
      }
    __syncthreads();
    #pragma unroll
    for (int i = 0; i < 8; i++){
      int c = tid + 256 * i;
      int nl = c >> 5, jj = c & 31;
      int nd = nbb + nl;
      if (nd < N)
        *(float4*)(fout + (size_t)nd * D + jj * 4) = *(const float4*)(ftile + nl * FS + jj * 4);
    }
  }
}

extern "C" void kernel_launch(void* const* d_in, const int* in_sizes, int n_in,
                              void* d_out, int out_size, void* d_ws, size_t ws_size,
                              hipStream_t stream){
  const float* x     = (const float*)d_in[0];
  const int*   edges = (const int*)d_in[1];
  const float* dp_w  = (const float*)d_in[2];
  const float* dp_b  = (const float*)d_in[3];
  const float* sc_w  = (const float*)d_in[4];
  const float* sc_b  = (const float*)d_in[5];
  const float* g1_lw = (const float*)d_in[6];
  const float* g1_lb = (const float*)d_in[7];
  const float* g1_rw = (const float*)d_in[8];
  const float* n1_g  = (const float*)d_in[9];
  const float* n1_b  = (const float*)d_in[10];
  const float* g2_lw = (const float*)d_in[11];
  const float* g2_lb = (const float*)d_in[12];
  const float* g2_rw = (const float*)d_in[13];
  const float* n2_g  = (const float*)d_in[14];
  const float* n2_b  = (const float*)d_in[15];

  const int N = in_sizes[0] / D;
  const int E = in_sizes[1] / 2;
  const int* esrc = edges;
  const int* edst = edges + E;
  const int nbuck = (N + 127) >> 7;         // 391 for N=50000 (<=512)
  const int epb = (E + PB - 1) / PB;

  char* base = (char*)d_ws;
  size_t cur = 0;
  auto carve = [&](size_t b) -> char* {
    char* p = base + cur;
    cur = (cur + b + 255) & ~(size_t)255;
    return p;
  };
  unsigned* ebuf = (unsigned*)carve((size_t)E * 4);
  int* cnt       = (int*)carve((size_t)PB * nbuck * 4);
  int* offs      = (int*)carve((size_t)PB * nbuck * 4);
  int* bbase     = (int*)carve((size_t)(nbuck + 1) * 4);
  int* off       = (int*)carve((size_t)(N + 1) * 4);
  int* csr       = (int*)carve((size_t)E * 4);
  unsigned short* wb    = (unsigned short*)carve((size_t)3 * 32768 * 2);
  unsigned short* hbuf  = (unsigned short*)carve((size_t)N * D * 2);
  unsigned short* h1buf = (unsigned short*)carve((size_t)N * D * 2);
  unsigned short* sbuf  = (unsigned short*)carve((size_t)N * D * 2);

  unsigned short* wp0 = wb;
  unsigned short* wp1 = wb + 32768;
  unsigned short* wp2 = wb + 2 * 32768;

  float* out = (float*)d_out;

  k_prep<<<48, 256, 0, stream>>>(sc_w, dp_w, g1_lw, g1_rw, g2_lw, g2_rw, wb);
  k_pcount<<<PB, 256, 0, stream>>>(edst, cnt, E, nbuck, epb);
  k_pscan<<<1, 256, 0, stream>>>(cnt, offs, bbase, E, nbuck);
  k_pscatter<<<PB, 256, 0, stream>>>(esrc, edst, offs, ebuf, E, nbuck, epb);
  k_csr<<<nbuck, 256, 0, stream>>>(ebuf, bbase, off, csr, N, E);

  const int nin = (N + 63) / 64;
  k_in<<<nin, 256, 0, stream>>>(x, wp0, sc_b, dp_b, sbuf, hbuf, N);

  k_gf<<<nin, 256, 17408, stream>>>(hbuf, off, csr, wp1, g1_lb, n1_g, n1_b,
                                    nullptr, h1buf, nullptr, N, 0);
  k_gf<<<nin, 256, 33792, stream>>>(h1buf, off, csr, wp2, g2_lb, n2_g, n2_b,
                                    sbuf, nullptr, out, N, 1);
}

// Round 7
// 248.128 us; speedup vs baseline: 5.3019x; 1.0716x over previous
//
#include <hip/hip_runtime.h>
#include <hip/hip_bf16.h>
#include <math.h>

#define D 128
#define WS 136            // LDS row stride in shorts
#define FS 132            // LDS row stride in floats
#define PB 128            // partition blocks

typedef __attribute__((ext_vector_type(8))) short bf16x8;
typedef __attribute__((ext_vector_type(4))) float f32x4;

__device__ __forceinline__ unsigned short f2bf(float f){
  return (unsigned short)((__float_as_uint(f) + 0x8000u) >> 16);
}
__device__ __forceinline__ float bf2f(unsigned short h){
  return __uint_as_float(((unsigned)h) << 16);
}
__device__ __forceinline__ float bf2f_lo(unsigned v){
  return __uint_as_float(v << 16);
}
__device__ __forceinline__ float bf2f_hi(unsigned v){
  return __uint_as_float(v & 0xFFFF0000u);
}
__device__ __forceinline__ float gelu_fast(float v){
  float u = v * v;
  float arg = v * (1.5957691216f + 0.0713548163f * u);
  arg = fminf(arg, 60.0f);
  float e = __expf(arg);
  return v * e * __builtin_amdgcn_rcpf(e + 1.0f);
}

// ---- fused: weight convert (blocks 0..47) + bucket count (blocks 48..48+PB) ----
__global__ __launch_bounds__(256) void k_prepcnt(const float* s0, const float* s1,
    const float* s2, const float* s3, const float* s4, const float* s5,
    unsigned short* dst, const int* __restrict__ edst, int* __restrict__ cnt,
    int E, int nbuck, int epb){
  __shared__ int hist[512];
  if (blockIdx.x < 48){
    int gt = blockIdx.x * 256 + threadIdx.x;   // 0..12287
    int m = gt >> 11;
    int r = gt & 2047;
    int f = r >> 6, lane = r & 63;
    int t = f & 7, kk = f >> 3;
    int row = t * 16 + (lane & 15);
    int col = kk * 32 + (lane >> 4) * 8;
    const float* src;
    if (m == 0) src = s0; else if (m == 1) src = s1; else if (m == 2) src = s2;
    else if (m == 3) src = s3; else if (m == 4) src = s4; else src = s5;
    src += row * 128 + col;
    float4 a = *(const float4*)src;
    float4 bb = *(const float4*)(src + 4);
    bf16x8 o;
    o[0] = (short)f2bf(a.x);  o[1] = (short)f2bf(a.y);
    o[2] = (short)f2bf(a.z);  o[3] = (short)f2bf(a.w);
    o[4] = (short)f2bf(bb.x); o[5] = (short)f2bf(bb.y);
    o[6] = (short)f2bf(bb.z); o[7] = (short)f2bf(bb.w);
    int pair = m >> 1, half = m & 1;
    *(bf16x8*)(dst + (size_t)pair * 32768 + (((size_t)f * 2 + half) * 64 + lane) * 8) = o;
    return;
  }
  int blk = blockIdx.x - 48;
  for (int b = threadIdx.x; b < nbuck; b += 256) hist[b] = 0;
  __syncthreads();
  int start = blk * epb;
  int end = min(E, start + epb);
  for (int e = start + threadIdx.x; e < end; e += 256)
    atomicAdd(&hist[edst[e] >> 7], 1);
  __syncthreads();
  for (int b = threadIdx.x; b < nbuck; b += 256) cnt[blk * nbuck + b] = hist[b];
}

// ---- bucket scan (single block) ----
__global__ __launch_bounds__(256) void k_pscan(const int* __restrict__ cnt,
    int* __restrict__ offs, int* __restrict__ bbase, int E, int nbuck){
  __shared__ int tot[512], base[512];
  int t = threadIdx.x;
  for (int b = t; b < nbuck; b += 256){
    int s = 0;
    for (int blk = 0; blk < PB; blk++) s += cnt[blk * nbuck + b];
    tot[b] = s;
  }
  __syncthreads();
  for (int b = t; b < nbuck; b += 256){
    int s = 0;
    for (int j = 0; j < b; j++) s += tot[j];
    base[b] = s;
  }
  __syncthreads();
  for (int b = t; b < nbuck; b += 256){
    bbase[b] = base[b];
    int run = base[b];
    for (int blk = 0; blk < PB; blk++){
      offs[blk * nbuck + b] = run;
      run += cnt[blk * nbuck + b];
    }
  }
  if (t == 0) bbase[nbuck] = E;
}

// ---- bucket scatter (LDS-only atomics) -> ebuf = src | dloc<<16 ----
__global__ __launch_bounds__(256) void k_pscatter(const int* __restrict__ esrc,
    const int* __restrict__ edst, const int* __restrict__ offs,
    unsigned* __restrict__ ebuf, int E, int nbuck, int epb){
  __shared__ int loff[512];
  for (int b = threadIdx.x; b < nbuck; b += 256) loff[b] = offs[blockIdx.x * nbuck + b];
  __syncthreads();
  int start = blockIdx.x * epb;
  int end = min(E, start + epb);
  for (int e = start + threadIdx.x; e < end; e += 256){
    int s = esrc[e], d = edst[e];
    int b = d >> 7;
    int pos = atomicAdd(&loff[b], 1);
    ebuf[pos] = (unsigned)s | ((unsigned)(d & 127) << 16);
  }
}

// ---- fused: per-bucket counting sort -> csr/off (blocks < nbuck)
//      + input layer GEMM (blocks >= nbuck) ----
__global__ __launch_bounds__(256) void k_csrin(
    const unsigned* __restrict__ ebuf, const int* __restrict__ bbase,
    int* __restrict__ off, int* __restrict__ csr,
    const float* __restrict__ x, const unsigned short* __restrict__ wp,
    const float* __restrict__ scb, const float* __restrict__ dpb,
    unsigned short* __restrict__ sbuf, unsigned short* __restrict__ hbuf,
    int N, int E, int nbuck){
  __shared__ int cnt[128], pref[128], curs[128];
  __shared__ unsigned short tile[64 * WS];
  int tid = threadIdx.x;
  if ((int)blockIdx.x < nbuck){
    int b = blockIdx.x;
    int start = bbase[b], end = bbase[b + 1];
    if (tid < 128) cnt[tid] = 0;
    __syncthreads();
    for (int e = start + tid; e < end; e += 256)
      atomicAdd(&cnt[ebuf[e] >> 16], 1);
    __syncthreads();
    if (tid < 128) pref[tid] = cnt[tid];
    __syncthreads();
    for (int ofs = 1; ofs < 128; ofs <<= 1){
      int v = 0;
      if (tid < 128 && tid >= ofs) v = pref[tid - ofs];
      __syncthreads();
      if (tid < 128) pref[tid] += v;
      __syncthreads();
    }
    if (tid < 128){
      int ex = pref[tid] - cnt[tid];
      curs[tid] = ex;
      int node = b * 128 + tid;
      if (node < N) off[node] = start + ex;
    }
    if (b == 0 && tid == 0) off[N] = E;
    __syncthreads();
    for (int e = start + tid; e < end; e += 256){
      unsigned u = ebuf[e];
      int d = u >> 16;
      int p = atomicAdd(&curs[d], 1);
      csr[start + p] = (int)(u & 0xFFFFu);
    }
    return;
  }
  // ---- k_in part ----
  int bx = blockIdx.x - nbuck;
  int w = tid >> 6, lane = tid & 63, quad = lane >> 4, l16 = lane & 15;
  int nbb = bx * 64;
  int nb = nbb + w * 16;
  int arow = min(nb + l16, N - 1);
  f32x4 acc[2][8];
  #pragma unroll
  for (int m = 0; m < 2; m++)
    #pragma unroll
    for (int t = 0; t < 8; t++) acc[m][t] = (f32x4){0.f, 0.f, 0.f, 0.f};
  #pragma unroll
  for (int kk = 0; kk < 4; kk++){
    const float* xp = x + (size_t)arow * D + kk * 32 + quad * 8;
    float4 xa = *(const float4*)xp;
    float4 xb = *(const float4*)(xp + 4);
    bf16x8 a;
    a[0] = (short)f2bf(xa.x); a[1] = (short)f2bf(xa.y);
    a[2] = (short)f2bf(xa.z); a[3] = (short)f2bf(xa.w);
    a[4] = (short)f2bf(xb.x); a[5] = (short)f2bf(xb.y);
    a[6] = (short)f2bf(xb.z); a[7] = (short)f2bf(xb.w);
    #pragma unroll
    for (int t = 0; t < 8; t++){
      size_t fo = (((size_t)(kk * 8 + t) * 2) * 64 + lane) * 8;
      bf16x8 b0 = *(const bf16x8*)(wp + fo);
      bf16x8 b1 = *(const bf16x8*)(wp + fo + 512);
      acc[0][t] = __builtin_amdgcn_mfma_f32_16x16x32_bf16(a, b0, acc[0][t], 0, 0, 0);
      acc[1][t] = __builtin_amdgcn_mfma_f32_16x16x32_bf16(a, b1, acc[1][t], 0, 0, 0);
    }
  }
  #pragma unroll
  for (int m = 0; m < 2; m++){
    const float* bias = m ? dpb : scb;
    #pragma unroll
    for (int t = 0; t < 8; t++){
      float bv = bias[t * 16 + l16];
      #pragma unroll
      for (int r = 0; r < 4; r++){
        int nl = w * 16 + quad * 4 + r;
        float v = acc[m][t][r] + bv;
        if (m) v = gelu_fast(v);
        tile[nl * WS + t * 16 + l16] = f2bf(v);
      }
    }
    __syncthreads();
    unsigned short* dst = m ? hbuf : sbuf;
    #pragma unroll
    for (int i = 0; i < 4; i++){
      int c = tid + 256 * i;
      int nl = c >> 4, j = c & 15;
      int node = nbb + nl;
      if (node < N)
        *(bf16x8*)(dst + (size_t)node * D + j * 8) = *(const bf16x8*)(tile + nl * WS + j * 8);
    }
    __syncthreads();
  }
}

// ---- mean aggregation v3: quarter-wave (16 lanes x 16B = full row) owns
//      2 sequential nodes; unroll 4 -> 16 rows in flight per wave ----
__global__ __launch_bounds__(256) void k_agg3(const unsigned short* __restrict__ h,
    const int* __restrict__ off, const int* __restrict__ csr,
    unsigned short* __restrict__ mbuf, int N){
  int tid = threadIdx.x;
  int wq = tid >> 4;                 // quarter index in block: 0..15
  int l16 = tid & 15;
  int base_node = blockIdx.x * 32 + wq * 2;
  float a[2][8];
  #pragma unroll
  for (int s = 0; s < 2; s++)
    #pragma unroll
    for (int c = 0; c < 8; c++) a[s][c] = 0.f;
  #pragma unroll
  for (int s = 0; s < 2; s++){
    int node = base_node + s;
    if (node < N){
      int e = off[node], e1 = off[node + 1];
      for (; e + 3 < e1; e += 4){
        int n0 = csr[e], n1 = csr[e + 1], n2 = csr[e + 2], n3 = csr[e + 3];
        uint4 v0 = *(const uint4*)(h + (size_t)n0 * D + l16 * 8);
        uint4 v1 = *(const uint4*)(h + (size_t)n1 * D + l16 * 8);
        uint4 v2 = *(const uint4*)(h + (size_t)n2 * D + l16 * 8);
        uint4 v3 = *(const uint4*)(h + (size_t)n3 * D + l16 * 8);
        a[s][0] += bf2f_lo(v0.x) + bf2f_lo(v1.x) + bf2f_lo(v2.x) + bf2f_lo(v3.x);
        a[s][1] += bf2f_hi(v0.x) + bf2f_hi(v1.x) + bf2f_hi(v2.x) + bf2f_hi(v3.x);
        a[s][2] += bf2f_lo(v0.y) + bf2f_lo(v1.y) + bf2f_lo(v2.y) + bf2f_lo(v3.y);
        a[s][3] += bf2f_hi(v0.y) + bf2f_hi(v1.y) + bf2f_hi(v2.y) + bf2f_hi(v3.y);
        a[s][4] += bf2f_lo(v0.z) + bf2f_lo(v1.z) + bf2f_lo(v2.z) + bf2f_lo(v3.z);
        a[s][5] += bf2f_hi(v0.z) + bf2f_hi(v1.z) + bf2f_hi(v2.z) + bf2f_hi(v3.z);
        a[s][6] += bf2f_lo(v0.w) + bf2f_lo(v1.w) + bf2f_lo(v2.w) + bf2f_lo(v3.w);
        a[s][7] += bf2f_hi(v0.w) + bf2f_hi(v1.w) + bf2f_hi(v2.w) + bf2f_hi(v3.w);
      }
      for (; e < e1; e++){
        int n0 = csr[e];
        uint4 v0 = *(const uint4*)(h + (size_t)n0 * D + l16 * 8);
        a[s][0] += bf2f_lo(v0.x); a[s][1] += bf2f_hi(v0.x);
        a[s][2] += bf2f_lo(v0.y); a[s][3] += bf2f_hi(v0.y);
        a[s][4] += bf2f_lo(v0.z); a[s][5] += bf2f_hi(v0.z);
        a[s][6] += bf2f_lo(v0.w); a[s][7] += bf2f_hi(v0.w);
      }
    }
  }
  #pragma unroll
  for (int s = 0; s < 2; s++){
    int node = base_node + s;
    if (node < N){
      int deg = off[node + 1] - off[node];
      float inv = 1.0f / (float)(deg > 1 ? deg : 1);
      uint4 o;
      o.x = ((unsigned)f2bf(a[s][1] * inv) << 16) | f2bf(a[s][0] * inv);
      o.y = ((unsigned)f2bf(a[s][3] * inv) << 16) | f2bf(a[s][2] * inv);
      o.z = ((unsigned)f2bf(a[s][5] * inv) << 16) | f2bf(a[s][4] * inv);
      o.w = ((unsigned)f2bf(a[s][7] * inv) << 16) | f2bf(a[s][6] * inv);
      *(uint4*)(mbuf + (size_t)node * D + l16 * 8) = o;
    }
  }
}

// ---- SAGE layer GEMM: 16 nodes/wave, 64/block; acc = mean@wl^T + lb + h@wr^T;
//      LN; mode0: gelu -> bf16 hout; mode1: gelu(LN + shortcut) -> fp32 fout ----
__global__ __launch_bounds__(256) void k_g(
    const unsigned short* __restrict__ hin, const unsigned short* __restrict__ mbuf,
    const unsigned short* __restrict__ wp,
    const float* __restrict__ lb, const float* __restrict__ gamma,
    const float* __restrict__ beta,
    const unsigned short* __restrict__ sbuf,
    unsigned short* __restrict__ hout, float* __restrict__ fout, int N, int mode){
  extern __shared__ char smraw[];
  unsigned short* stile = (unsigned short*)smraw;
  float* ftile = (float*)smraw;
  int tid = threadIdx.x, w = tid >> 6, lane = tid & 63, quad = lane >> 4, l16 = lane & 15;
  int nbb = blockIdx.x * 64;
  int nb = nbb + w * 16;
  int arow = min(nb + l16, N - 1);
  f32x4 acc[8];
  #pragma unroll
  for (int t = 0; t < 8; t++) acc[t] = (f32x4){0.f, 0.f, 0.f, 0.f};
  #pragma unroll
  for (int kk = 0; kk < 4; kk++){
    int co = kk * 32 + quad * 8;
    bf16x8 am = *(const bf16x8*)(mbuf + (size_t)arow * D + co);
    bf16x8 ah = *(const bf16x8*)(hin + (size_t)arow * D + co);
    #pragma unroll
    for (int t = 0; t < 8; t++){
      size_t fo = (((size_t)(kk * 8 + t) * 2) * 64 + lane) * 8;
      bf16x8 bl = *(const bf16x8*)(wp + fo);
      bf16x8 br = *(const bf16x8*)(wp + fo + 512);
      acc[t] = __builtin_amdgcn_mfma_f32_16x16x32_bf16(am, bl, acc[t], 0, 0, 0);
      acc[t] = __builtin_amdgcn_mfma_f32_16x16x32_bf16(ah, br, acc[t], 0, 0, 0);
    }
  }
  float lbv[8], gv[8], bv[8];
  #pragma unroll
  for (int t = 0; t < 8; t++){
    lbv[t] = lb[t * 16 + l16];
    gv[t] = gamma[t * 16 + l16];
    bv[t] = beta[t * 16 + l16];
  }
  float mu[4], rs[4];
  #pragma unroll
  for (int r = 0; r < 4; r++){
    float s = 0.f, qq = 0.f;
    #pragma unroll
    for (int t = 0; t < 8; t++){
      float v = acc[t][r] + lbv[t];
      acc[t][r] = v;
      s += v; qq += v * v;
    }
    s += __shfl_xor(s, 1); qq += __shfl_xor(qq, 1);
    s += __shfl_xor(s, 2); qq += __shfl_xor(qq, 2);
    s += __shfl_xor(s, 4); qq += __shfl_xor(qq, 4);
    s += __shfl_xor(s, 8); qq += __shfl_xor(qq, 8);
    float m_ = s * (1.f / 128.f);
    mu[r] = m_;
    rs[r] = rsqrtf(qq * (1.f / 128.f) - m_ * m_ + 1e-5f);
  }
  if (mode == 0){
    #pragma unroll
    for (int t = 0; t < 8; t++)
      #pragma unroll
      for (int r = 0; r < 4; r++){
        int nl = w * 16 + quad * 4 + r;
        float v = (acc[t][r] - mu[r]) * rs[r] * gv[t] + bv[t];
        stile[nl * WS + t * 16 + l16] = f2bf(gelu_fast(v));
      }
    __syncthreads();
    #pragma unroll
    for (int i = 0; i < 4; i++){
      int c = tid + 256 * i;
      int nl = c >> 4, j = c & 15;
      int node = nbb + nl;
      if (node < N)
        *(bf16x8*)(hout + (size_t)node * D + j * 8) = *(const bf16x8*)(stile + nl * WS + j * 8);
    }
  } else {
    #pragma unroll
    for (int i = 0; i < 4; i++){
      int c = tid + 256 * i;
      int nl = c >> 4, j = c & 15;
      int node = nbb + nl;
      bf16x8 v = (bf16x8){0,0,0,0,0,0,0,0};
      if (node < N) v = *(const bf16x8*)(sbuf + (size_t)node * D + j * 8);
      *(bf16x8*)(stile + nl * WS + j * 8) = v;
    }
    __syncthreads();
    float sc[8][4];
    #pragma unroll
    for (int t = 0; t < 8; t++)
      #pragma unroll
      for (int r = 0; r < 4; r++){
        int nl = w * 16 + quad * 4 + r;
        sc[t][r] = bf2f(stile[nl * WS + t * 16 + l16]);
      }
    __syncthreads();
    #pragma unroll
    for (int t = 0; t < 8; t++)
      #pragma unroll
      for (int r = 0; r < 4; r++){
        int nl = w * 16 + quad * 4 + r;
        float v = (acc[t][r] - mu[r]) * rs[r] * gv[t] + bv[t];
        ftile[nl * FS + t * 16 + l16] = gelu_fast(v + sc[t][r]);
      }
    __syncthreads();
    #pragma unroll
    for (int i = 0; i < 8; i++){
      int c = tid + 256 * i;
      int nl = c >> 5, j = c & 31;
      int node = nbb + nl;
      if (node < N)
        *(float4*)(fout + (size_t)node * D + j * 4) = *(const float4*)(ftile + nl * FS + j * 4);
    }
  }
}

extern "C" void kernel_launch(void* const* d_in, const int* in_sizes, int n_in,
                              void* d_out, int out_size, void* d_ws, size_t ws_size,
                              hipStream_t stream){
  const float* x     = (const float*)d_in[0];
  const int*   edges = (const int*)d_in[1];
  const float* dp_w  = (const float*)d_in[2];
  const float* dp_b  = (const float*)d_in[3];
  const float* sc_w  = (const float*)d_in[4];
  const float* sc_b  = (const float*)d_in[5];
  const float* g1_lw = (const float*)d_in[6];
  const float* g1_lb = (const float*)d_in[7];
  const float* g1_rw = (const float*)d_in[8];
  const float* n1_g  = (const float*)d_in[9];
  const float* n1_b  = (const float*)d_in[10];
  const float* g2_lw = (const float*)d_in[11];
  const float* g2_lb = (const float*)d_in[12];
  const float* g2_rw = (const float*)d_in[13];
  const float* n2_g  = (const float*)d_in[14];
  const float* n2_b  = (const float*)d_in[15];

  const int N = in_sizes[0] / D;
  const int E = in_sizes[1] / 2;
  const int* esrc = edges;
  const int* edst = edges + E;
  const int nbuck = (N + 127) >> 7;
  const int epb = (E + PB - 1) / PB;

  char* base = (char*)d_ws;
  size_t cur = 0;
  auto carve = [&](size_t b) -> char* {
    char* p = base + cur;
    cur = (cur + b + 255) & ~(size_t)255;
    return p;
  };
  unsigned* ebuf = (unsigned*)carve((size_t)E * 4);
  int* cnt       = (int*)carve((size_t)PB * nbuck * 4);
  int* offs      = (int*)carve((size_t)PB * nbuck * 4);
  int* bbase     = (int*)carve((size_t)(nbuck + 1) * 4);
  int* off       = (int*)carve((size_t)(N + 1) * 4);
  int* csr       = (int*)carve((size_t)E * 4);
  unsigned short* wb    = (unsigned short*)carve((size_t)3 * 32768 * 2);
  unsigned short* hbuf  = (unsigned short*)carve((size_t)N * D * 2);
  unsigned short* h1buf = (unsigned short*)carve((size_t)N * D * 2);
  unsigned short* mbuf  = (unsigned short*)carve((size_t)N * D * 2);
  unsigned short* sbuf  = (unsigned short*)carve((size_t)N * D * 2);

  unsigned short* wp0 = wb;
  unsigned short* wp1 = wb + 32768;
  unsigned short* wp2 = wb + 2 * 32768;

  float* out = (float*)d_out;

  k_prepcnt<<<48 + PB, 256, 0, stream>>>(sc_w, dp_w, g1_lw, g1_rw, g2_lw, g2_rw,
                                         wb, edst, cnt, E, nbuck, epb);
  k_pscan<<<1, 256, 0, stream>>>(cnt, offs, bbase, E, nbuck);
  k_pscatter<<<PB, 256, 0, stream>>>(esrc, edst, offs, ebuf, E, nbuck, epb);

  const int nin = (N + 63) / 64;
  k_csrin<<<nbuck + nin, 256, 0, stream>>>(ebuf, bbase, off, csr,
                                           x, wp0, sc_b, dp_b, sbuf, hbuf,
                                           N, E, nbuck);

  const int nagg = (N + 31) / 32;
  k_agg3<<<nagg, 256, 0, stream>>>(hbuf, off, csr, mbuf, N);
  k_g<<<nin, 256, 17408, stream>>>(hbuf, mbuf, wp1, g1_lb, n1_g, n1_b,
                                   nullptr, h1buf, nullptr, N, 0);
  k_agg3<<<nagg, 256, 0, stream>>>(h1buf, off, csr, mbuf, N);
  k_g<<<nin, 256, 33792, stream>>>(h1buf, mbuf, wp2, g2_lb, n2_g, n2_b,
                                   sbuf, nullptr, out, N, 1);
}